// Round 1
// baseline (351.684 us; speedup 1.0000x reference)
//
#include <hip/hip_runtime.h>

#define NN 8
#define CC 19
#define HH 512
#define WW 512
#define HW (HH*WW)            // 262144
#define NPIX (NN*HW)          // 2097152
#define NPLANE (NN*CC)        // 152
#define BIGV (1<<20)

// persistent scratch in device globals (avoids ws_size uncertainty)
__device__ unsigned char g_t[NPIX];
__device__ unsigned char g_pred[NPIX];
__device__ float g_lse[NPIX];
__device__ unsigned char g_inter[(size_t)NPLANE * HW];
__device__ float g_acc[2];      // [0]=ce, [1]=border
__device__ float g_present[CC];

__global__ void k_init() {
  int t = threadIdx.x;
  if (t < 2) g_acc[t] = 0.f;
  if (t < CC) g_present[t] = 0.f;
}

// per-pixel: softmax stats over 19 channels, CE, argmax, lse, t/pred u8 planes
__global__ __launch_bounds__(256) void k_pixel(const float* __restrict__ slices,
                                               const int* __restrict__ targets) {
  int tid = blockIdx.x * 256 + threadIdx.x;
  int stride = gridDim.x * 256;
  float ce_local = 0.f;
  for (int p = tid; p < NPIX; p += stride) {
    int n = p >> 18;            // HW = 2^18
    int r = p & (HW - 1);
    const float* base = slices + (size_t)n * CC * HW + r;
    float xs[CC];
#pragma unroll
    for (int c = 0; c < CC; ++c) xs[c] = base[(size_t)c * HW];
    float m = xs[0]; int am = 0;
#pragma unroll
    for (int c = 1; c < CC; ++c) { if (xs[c] > m) { m = xs[c]; am = c; } }
    float se = 0.f;
#pragma unroll
    for (int c = 0; c < CC; ++c) se += __expf(xs[c] - m);
    float lsev = m + __logf(se);
    int t = targets[p];
    if (t != 255) {
      float picked = 0.f;
#pragma unroll
      for (int c = 0; c < CC; ++c) picked = (c == t) ? xs[c] : picked;
      ce_local += lsev - picked;   // = -(logp picked)
    }
    g_lse[p] = lsev;
    g_pred[p] = (unsigned char)am;
    g_t[p] = (unsigned char)t;
    if ((unsigned)t < CC) g_present[t] = 1.f;   // benign race
  }
  __shared__ float sred[256];
  sred[threadIdx.x] = ce_local;
  __syncthreads();
  for (int s = 128; s > 0; s >>= 1) {
    if (threadIdx.x < s) sred[threadIdx.x] += sred[threadIdx.x + s];
    __syncthreads();
  }
  if (threadIdx.x == 0) atomicAdd(&g_acc[0], sred[0]);
}

// W-axis min-plus scan (fwd+bwd) per (n,c,h) row; one wave per row.
// lane owns 8 consecutive w; wave-level scan via shuffles on the
// (value - 8*lane) trick for the min(c, x+len) semiring.
__global__ __launch_bounds__(256) void k_rowdt() {
  int wid = blockIdx.x * 4 + (threadIdx.x >> 6);
  int lane = threadIdx.x & 63;
  int c = wid % CC;
  int q = wid / CC;
  int h = q % HH;
  int n = q / HH;

  const unsigned char* trow = g_t + (size_t)(n * HH + h) * WW + lane * 8;
  uint2 tc8 = *(const uint2*)trow;
  uint2 tn8 = (h + 1 < HH) ? *(const uint2*)(trow + WW) : tc8;  // h=H-1: tb -> 0
  int prev_last = __shfl_up((int)((tc8.y >> 24) & 255), 1, 64);

  int tb_[8], tn_[8];
#pragma unroll
  for (int k = 0; k < 4; ++k) {
    tb_[k]     = (tc8.x >> (k * 8)) & 255;
    tb_[k + 4] = (tc8.y >> (k * 8)) & 255;
    tn_[k]     = (tn8.x >> (k * 8)) & 255;
    tn_[k + 4] = (tn8.y >> (k * 8)) & 255;
  }
  int d0[8];
#pragma unroll
  for (int k = 0; k < 8; ++k) {
    bool ec = (tb_[k] == c);
    bool en = (tn_[k] == c);
    int left = (k > 0) ? tb_[k - 1] : ((lane > 0) ? prev_last : tb_[0]); // w=0: lr->0
    bool el = (left == c);
    bool bb = (ec != en) || (ec != el);
    d0[k] = bb ? 0 : 255;   // penalty saturated to 255 (exact for this data)
  }
  // forward scan
  int ls[8];
  ls[0] = d0[0];
#pragma unroll
  for (int k = 1; k < 8; ++k) ls[k] = min(d0[k], ls[k - 1] + 1);
  int u = ls[7] - 8 * lane;
#pragma unroll
  for (int o = 1; o < 64; o <<= 1) {
    int t = __shfl_up(u, o, 64);
    if (lane >= o) u = min(u, t);
  }
  int cf = __shfl_up(u, 1, 64);
  int carry = (lane == 0) ? BIGV : cf + 8 * (lane - 1);
  int f[8];
#pragma unroll
  for (int k = 0; k < 8; ++k) f[k] = min(ls[k], carry + k + 1);
  // backward scan
  int bs[8];
  bs[7] = f[7];
#pragma unroll
  for (int k = 6; k >= 0; --k) bs[k] = min(f[k], bs[k + 1] + 1);
  int mm = bs[0] + 8 * lane;
#pragma unroll
  for (int o = 1; o < 64; o <<= 1) {
    int t = __shfl_down(mm, o, 64);
    if (lane + o < 64) mm = min(mm, t);
  }
  int mb = __shfl_down(mm, 1, 64);
  int carryb = (lane == 63) ? BIGV : mb - 8 * lane;
  unsigned int lo = 0, hi = 0;
#pragma unroll
  for (int k = 0; k < 8; ++k) {
    int v = min(bs[k], carryb - k);
    if (k < 4) lo |= (unsigned int)v << (k * 8);
    else       hi |= (unsigned int)v << ((k - 4) * 8);
  }
  *(uint2*)(g_inter + ((size_t)(n * CC + c) * HH + h) * WW + lane * 8) =
      make_uint2(lo, hi);
}

// H-axis scan per (n,c,w) column: descending pass (in-place), then ascending
// pass fused with the sparse border accumulation.
__global__ __launch_bounds__(256) void k_coldt(const float* __restrict__ slices) {
  int plane = blockIdx.x >> 1;
  int wb = (blockIdx.x & 1) * 256;
  int c = plane % CC;
  int n = plane / CC;
  int w = wb + threadIdx.x;
  size_t pbase = (size_t)plane * HW;
  unsigned char* col = g_inter + pbase + w;

  int prev = BIGV;
  for (int h = HH - 1; h >= 0; --h) {
    int v = col[(size_t)h * WW];
    v = min(v, prev + 1);
    col[(size_t)h * WW] = (unsigned char)v;
    prev = v;
  }
  float acc = 0.f;
  int carry = BIGV;
  float pres = g_present[c];
  for (int h = 0; h < HH; ++h) {
    int v = col[(size_t)h * WW];
    v = min(v, carry + 1);
    carry = v;
    int d = v - 5;           // BORDER_DILATE
    if (d > 0) {
      int pix = (n * HH + h) * WW + w;
      int pcv = g_pred[pix];
      int pnv = (h + 1 < HH) ? g_pred[pix + WW] : pcv;
      int plv = (w > 0) ? g_pred[pix - 1] : pcv;
      bool ec = (pcv == c);
      if ((ec != (pnv == c)) || (ec != (plv == c))) {
        float x = slices[pbase + (size_t)h * WW + w];   // slices plane == inter plane index
        float smv = __expf(x - g_lse[pix]);
        acc += smv * (float)d;
      }
    }
  }
  __shared__ float sred[256];
  sred[threadIdx.x] = acc;
  __syncthreads();
  for (int s = 128; s > 0; s >>= 1) {
    if (threadIdx.x < s) sred[threadIdx.x] += sred[threadIdx.x + s];
    __syncthreads();
  }
  if (threadIdx.x == 0) atomicAdd(&g_acc[1], sred[0] * pres);
}

__global__ void k_final(float* __restrict__ out) {
  out[0] = g_acc[0] + sqrtf(g_acc[1]);   // BORDER_WEIGHT=1, power=0.5
}

extern "C" void kernel_launch(void* const* d_in, const int* in_sizes, int n_in,
                              void* d_out, int out_size, void* d_ws, size_t ws_size,
                              hipStream_t stream) {
  const float* slices = (const float*)d_in[0];
  const int* targets = (const int*)d_in[1];
  float* out = (float*)d_out;
  (void)d_ws; (void)ws_size; (void)in_sizes; (void)n_in; (void)out_size;

  hipLaunchKernelGGL(k_init, dim3(1), dim3(32), 0, stream);
  hipLaunchKernelGGL(k_pixel, dim3(2048), dim3(256), 0, stream, slices, targets);
  hipLaunchKernelGGL(k_rowdt, dim3((NN * CC * HH) / 4), dim3(256), 0, stream);
  hipLaunchKernelGGL(k_coldt, dim3(NPLANE * 2), dim3(256), 0, stream, slices);
  hipLaunchKernelGGL(k_final, dim3(1), dim3(1), 0, stream, out);
}

// Round 2
// 163.957 us; speedup vs baseline: 2.1450x; 2.1450x over previous
//
#include <hip/hip_runtime.h>

#define NN 8
#define CC 19
#define HH 512
#define WW 512
#define HW (HH*WW)            // 262144
#define NPIX (NN*HW)          // 2097152
#define NPLANE (NN*CC)        // 152
#define BIGV (1<<20)

// persistent scratch in device globals (avoids ws_size uncertainty)
__device__ unsigned char g_t[NPIX];
__device__ unsigned char g_pred[NPIX];
__device__ float g_lse[NPIX];
__device__ unsigned char g_inter[(size_t)NPLANE * HW];
__device__ float g_acc[2];      // [0]=ce, [1]=border
__device__ float g_present[CC];

__global__ void k_init() {
  int t = threadIdx.x;
  if (t < 2) g_acc[t] = 0.f;
  if (t < CC) g_present[t] = 0.f;
}

// per-pixel: softmax stats over 19 channels, CE, argmax, lse, t/pred u8 planes
__global__ __launch_bounds__(256) void k_pixel(const float* __restrict__ slices,
                                               const int* __restrict__ targets) {
  int tid = blockIdx.x * 256 + threadIdx.x;
  int stride = gridDim.x * 256;
  float ce_local = 0.f;
  for (int p = tid; p < NPIX; p += stride) {
    int n = p >> 18;            // HW = 2^18
    int r = p & (HW - 1);
    const float* base = slices + (size_t)n * CC * HW + r;
    float xs[CC];
#pragma unroll
    for (int c = 0; c < CC; ++c) xs[c] = base[(size_t)c * HW];
    float m = xs[0]; int am = 0;
#pragma unroll
    for (int c = 1; c < CC; ++c) { if (xs[c] > m) { m = xs[c]; am = c; } }
    float se = 0.f;
#pragma unroll
    for (int c = 0; c < CC; ++c) se += __expf(xs[c] - m);
    float lsev = m + __logf(se);
    int t = targets[p];
    if (t != 255) {
      float picked = 0.f;
#pragma unroll
      for (int c = 0; c < CC; ++c) picked = (c == t) ? xs[c] : picked;
      ce_local += lsev - picked;   // = -(logp picked)
    }
    g_lse[p] = lsev;
    g_pred[p] = (unsigned char)am;
    g_t[p] = (unsigned char)t;
    if ((unsigned)t < CC) g_present[t] = 1.f;   // benign race
  }
  __shared__ float sred[256];
  sred[threadIdx.x] = ce_local;
  __syncthreads();
  for (int s = 128; s > 0; s >>= 1) {
    if (threadIdx.x < s) sred[threadIdx.x] += sred[threadIdx.x + s];
    __syncthreads();
  }
  if (threadIdx.x == 0) atomicAdd(&g_acc[0], sred[0]);
}

// W-axis min-plus scan (fwd+bwd) per (n,c,h) row; one wave per row.
__global__ __launch_bounds__(256) void k_rowdt() {
  int wid = blockIdx.x * 4 + (threadIdx.x >> 6);
  int lane = threadIdx.x & 63;
  int c = wid % CC;
  int q = wid / CC;
  int h = q % HH;
  int n = q / HH;

  const unsigned char* trow = g_t + (size_t)(n * HH + h) * WW + lane * 8;
  uint2 tc8 = *(const uint2*)trow;
  uint2 tn8 = (h + 1 < HH) ? *(const uint2*)(trow + WW) : tc8;  // h=H-1: tb -> 0
  int prev_last = __shfl_up((int)((tc8.y >> 24) & 255), 1, 64);

  int tb_[8], tn_[8];
#pragma unroll
  for (int k = 0; k < 4; ++k) {
    tb_[k]     = (tc8.x >> (k * 8)) & 255;
    tb_[k + 4] = (tc8.y >> (k * 8)) & 255;
    tn_[k]     = (tn8.x >> (k * 8)) & 255;
    tn_[k + 4] = (tn8.y >> (k * 8)) & 255;
  }
  int d0[8];
#pragma unroll
  for (int k = 0; k < 8; ++k) {
    bool ec = (tb_[k] == c);
    bool en = (tn_[k] == c);
    int left = (k > 0) ? tb_[k - 1] : ((lane > 0) ? prev_last : tb_[0]); // w=0: lr->0
    bool el = (left == c);
    bool bb = (ec != en) || (ec != el);
    d0[k] = bb ? 0 : 255;   // penalty saturated to 255 (exact for this data)
  }
  // forward scan
  int ls[8];
  ls[0] = d0[0];
#pragma unroll
  for (int k = 1; k < 8; ++k) ls[k] = min(d0[k], ls[k - 1] + 1);
  int u = ls[7] - 8 * lane;
#pragma unroll
  for (int o = 1; o < 64; o <<= 1) {
    int t = __shfl_up(u, o, 64);
    if (lane >= o) u = min(u, t);
  }
  int cf = __shfl_up(u, 1, 64);
  int carry = (lane == 0) ? BIGV : cf + 8 * (lane - 1);
  int f[8];
#pragma unroll
  for (int k = 0; k < 8; ++k) f[k] = min(ls[k], carry + k + 1);
  // backward scan
  int bs[8];
  bs[7] = f[7];
#pragma unroll
  for (int k = 6; k >= 0; --k) bs[k] = min(f[k], bs[k + 1] + 1);
  int mm = bs[0] + 8 * lane;
#pragma unroll
  for (int o = 1; o < 64; o <<= 1) {
    int t = __shfl_down(mm, o, 64);
    if (lane + o < 64) mm = min(mm, t);
  }
  int mb = __shfl_down(mm, 1, 64);
  int carryb = (lane == 63) ? BIGV : mb - 8 * lane;
  unsigned int lo = 0, hi = 0;
#pragma unroll
  for (int k = 0; k < 8; ++k) {
    int v = min(bs[k], carryb - k);
    if (k < 4) lo |= (unsigned int)v << (k * 8);
    else       hi |= (unsigned int)v << ((k - 4) * 8);
  }
  *(uint2*)(g_inter + ((size_t)(n * CC + c) * HH + h) * WW + lane * 8) =
      make_uint2(lo, hi);
}

// H-axis DT via chunked scan-then-propagate: thread owns a 64-row chunk of
// one column in registers; cross-chunk carries exchanged through LDS.
// Fused with the sparse border accumulation. Nothing written back.
__global__ __launch_bounds__(512) void k_coldt(const float* __restrict__ slices) {
  int plane = blockIdx.x >> 3;          // 152 planes
  int wt = blockIdx.x & 7;              // 8 w-tiles of 64
  int hc = threadIdx.x >> 6;            // 8 h-chunks of 64
  int wl = threadIdx.x & 63;
  int c = plane % CC;
  int n = plane / CC;
  int w = wt * 64 + wl;
  size_t pbase = (size_t)plane * HW;
  const unsigned char* colbase = g_inter + pbase + (size_t)(hc * 64) * WW + w;

  // load 64 chunk values (independent coalesced 64B wave-loads)
  int v[64];
#pragma unroll
  for (int k = 0; k < 64; ++k) v[k] = colbase[(size_t)k * WW];

  // local forward min-plus scan in place: v[k] = min(d0[k], v[k-1]+1)
#pragma unroll
  for (int k = 1; k < 64; ++k) v[k] = min(v[k], v[k - 1] + 1);

  __shared__ int s_car[8][64];
  s_car[hc][wl] = v[63];
  __syncthreads();
  // forward cross-chunk carry: F_in(i+1) = min(f63(i)+1, F_in(i)+64)
  int F = BIGV;
#pragma unroll
  for (int i = 0; i < 7; ++i)
    if (i < hc) F = min(s_car[i][wl] + 1, F + 64);
#pragma unroll
  for (int k = 0; k < 64; ++k) v[k] = min(v[k], F + k);

  // local backward scan in place on F-result
#pragma unroll
  for (int k = 62; k >= 0; --k) v[k] = min(v[k], v[k + 1] + 1);

  __syncthreads();
  s_car[hc][wl] = v[0];
  __syncthreads();
  // backward cross-chunk carry: B_in(i) = min(g0(i+1)+1, B_in(i+1)+64)
  int B = BIGV;
#pragma unroll
  for (int j = 7; j >= 1; --j)
    if (j > hc) B = min(s_car[j][wl] + 1, B + 64);

  // fused sparse accumulation
  float acc = 0.f;
#pragma unroll
  for (int k = 0; k < 64; ++k) {
    int out = min(v[k], B + (63 - k));
    int d = out - 5;                    // BORDER_DILATE
    if (d > 0) {
      int h = hc * 64 + k;
      int pix = (n * HH + h) * WW + w;
      int pcv = g_pred[pix];
      int pnv = (h + 1 < HH) ? g_pred[pix + WW] : pcv;
      int plv = (w > 0) ? g_pred[pix - 1] : pcv;
      bool ec = (pcv == c);
      if ((ec != (pnv == c)) || (ec != (plv == c))) {
        float x = slices[pbase + (size_t)h * WW + w];
        float smv = __expf(x - g_lse[pix]);
        acc += smv * (float)d;
      }
    }
  }

  __shared__ float sred[512];
  sred[threadIdx.x] = acc;
  __syncthreads();
  for (int s = 256; s > 0; s >>= 1) {
    if (threadIdx.x < s) sred[threadIdx.x] += sred[threadIdx.x + s];
    __syncthreads();
  }
  if (threadIdx.x == 0) atomicAdd(&g_acc[1], sred[0] * g_present[c]);
}

__global__ void k_final(float* __restrict__ out) {
  out[0] = g_acc[0] + sqrtf(g_acc[1]);   // BORDER_WEIGHT=1, power=0.5
}

extern "C" void kernel_launch(void* const* d_in, const int* in_sizes, int n_in,
                              void* d_out, int out_size, void* d_ws, size_t ws_size,
                              hipStream_t stream) {
  const float* slices = (const float*)d_in[0];
  const int* targets = (const int*)d_in[1];
  float* out = (float*)d_out;
  (void)d_ws; (void)ws_size; (void)in_sizes; (void)n_in; (void)out_size;

  hipLaunchKernelGGL(k_init, dim3(1), dim3(32), 0, stream);
  hipLaunchKernelGGL(k_pixel, dim3(2048), dim3(256), 0, stream, slices, targets);
  hipLaunchKernelGGL(k_rowdt, dim3((NN * CC * HH) / 4), dim3(256), 0, stream);
  hipLaunchKernelGGL(k_coldt, dim3(NPLANE * 8), dim3(512), 0, stream, slices);
  hipLaunchKernelGGL(k_final, dim3(1), dim3(1), 0, stream, out);
}

// Round 3
// 160.550 us; speedup vs baseline: 2.1905x; 1.0212x over previous
//
#include <hip/hip_runtime.h>

#define NN 8
#define CC 19
#define HH 512
#define WW 512
#define HW (HH*WW)            // 262144
#define NPIX (NN*HW)          // 2097152
#define NPLANE (NN*CC)        // 152
#define BIGV (1<<20)

// persistent scratch in device globals (avoids ws_size uncertainty)
__device__ unsigned char g_t[NPIX];
__device__ unsigned char g_pred[NPIX];
__device__ float g_lse[NPIX];
__device__ unsigned char g_inter[(size_t)NPLANE * HW];
__device__ float g_acc[2];      // [0]=ce, [1]=border
__device__ float g_present[CC];

__global__ void k_init() {
  int t = threadIdx.x;
  if (t < 2) g_acc[t] = 0.f;
  if (t < CC) g_present[t] = 0.f;
}

// per-pixel softmax stats, vectorized 4 px/thread: float4 loads (16B/lane),
// uchar4/float4 stores. picked via cndmask chain (no runtime-indexed array).
__global__ __launch_bounds__(256) void k_pixel(const float* __restrict__ slices,
                                               const int* __restrict__ targets) {
  int tid = blockIdx.x * 256 + threadIdx.x;     // 524288 threads, 4 px each
  int p4 = tid * 4;
  int n = p4 >> 18;                             // HW = 2^18
  int r = p4 & (HW - 1);
  const float4* base = (const float4*)(slices + (size_t)n * CC * HW + r);

  float4 xs[CC];
#pragma unroll
  for (int c = 0; c < CC; ++c) xs[c] = base[(size_t)c * (HW / 4)];

  float m0 = xs[0].x, m1 = xs[0].y, m2 = xs[0].z, m3 = xs[0].w;
  int a0 = 0, a1 = 0, a2 = 0, a3 = 0;
#pragma unroll
  for (int c = 1; c < CC; ++c) {
    if (xs[c].x > m0) { m0 = xs[c].x; a0 = c; }
    if (xs[c].y > m1) { m1 = xs[c].y; a1 = c; }
    if (xs[c].z > m2) { m2 = xs[c].z; a2 = c; }
    if (xs[c].w > m3) { m3 = xs[c].w; a3 = c; }
  }
  float s0 = 0.f, s1 = 0.f, s2 = 0.f, s3 = 0.f;
#pragma unroll
  for (int c = 0; c < CC; ++c) {
    s0 += __expf(xs[c].x - m0);
    s1 += __expf(xs[c].y - m1);
    s2 += __expf(xs[c].z - m2);
    s3 += __expf(xs[c].w - m3);
  }
  float l0 = m0 + __logf(s0), l1 = m1 + __logf(s1);
  float l2 = m2 + __logf(s2), l3 = m3 + __logf(s3);

  int4 t4 = ((const int4*)targets)[tid];
  float p0 = 0.f, p1 = 0.f, p2 = 0.f, p3 = 0.f;
#pragma unroll
  for (int c = 0; c < CC; ++c) {
    p0 = (c == t4.x) ? xs[c].x : p0;
    p1 = (c == t4.y) ? xs[c].y : p1;
    p2 = (c == t4.z) ? xs[c].z : p2;
    p3 = (c == t4.w) ? xs[c].w : p3;
  }
  float ce_local = 0.f;
  if (t4.x != 255) ce_local += l0 - p0;
  if (t4.y != 255) ce_local += l1 - p1;
  if (t4.z != 255) ce_local += l2 - p2;
  if (t4.w != 255) ce_local += l3 - p3;

  ((float4*)g_lse)[tid] = make_float4(l0, l1, l2, l3);
  ((uchar4*)g_pred)[tid] = make_uchar4((unsigned char)a0, (unsigned char)a1,
                                       (unsigned char)a2, (unsigned char)a3);
  ((uchar4*)g_t)[tid] = make_uchar4((unsigned char)t4.x, (unsigned char)t4.y,
                                    (unsigned char)t4.z, (unsigned char)t4.w);
  if ((unsigned)t4.x < CC) g_present[t4.x] = 1.f;   // benign race
  if ((unsigned)t4.y < CC) g_present[t4.y] = 1.f;
  if ((unsigned)t4.z < CC) g_present[t4.z] = 1.f;
  if ((unsigned)t4.w < CC) g_present[t4.w] = 1.f;

  __shared__ float sred[256];
  sred[threadIdx.x] = ce_local;
  __syncthreads();
  for (int s = 128; s > 0; s >>= 1) {
    if (threadIdx.x < s) sred[threadIdx.x] += sred[threadIdx.x + s];
    __syncthreads();
  }
  if (threadIdx.x == 0) atomicAdd(&g_acc[0], sred[0]);
}

// W-axis min-plus scan (fwd+bwd) per (n,c,h) row; one wave per row.
__global__ __launch_bounds__(256) void k_rowdt() {
  int wid = blockIdx.x * 4 + (threadIdx.x >> 6);
  int lane = threadIdx.x & 63;
  int c = wid % CC;
  int q = wid / CC;
  int h = q % HH;
  int n = q / HH;

  const unsigned char* trow = g_t + (size_t)(n * HH + h) * WW + lane * 8;
  uint2 tc8 = *(const uint2*)trow;
  uint2 tn8 = (h + 1 < HH) ? *(const uint2*)(trow + WW) : tc8;  // h=H-1: tb -> 0
  int prev_last = __shfl_up((int)((tc8.y >> 24) & 255), 1, 64);

  int tb_[8], tn_[8];
#pragma unroll
  for (int k = 0; k < 4; ++k) {
    tb_[k]     = (tc8.x >> (k * 8)) & 255;
    tb_[k + 4] = (tc8.y >> (k * 8)) & 255;
    tn_[k]     = (tn8.x >> (k * 8)) & 255;
    tn_[k + 4] = (tn8.y >> (k * 8)) & 255;
  }
  int d0[8];
#pragma unroll
  for (int k = 0; k < 8; ++k) {
    bool ec = (tb_[k] == c);
    bool en = (tn_[k] == c);
    int left = (k > 0) ? tb_[k - 1] : ((lane > 0) ? prev_last : tb_[0]); // w=0: lr->0
    bool el = (left == c);
    bool bb = (ec != en) || (ec != el);
    d0[k] = bb ? 0 : 255;   // penalty saturated to 255 (exact for this data)
  }
  // forward scan
  int ls[8];
  ls[0] = d0[0];
#pragma unroll
  for (int k = 1; k < 8; ++k) ls[k] = min(d0[k], ls[k - 1] + 1);
  int u = ls[7] - 8 * lane;
#pragma unroll
  for (int o = 1; o < 64; o <<= 1) {
    int t = __shfl_up(u, o, 64);
    if (lane >= o) u = min(u, t);
  }
  int cf = __shfl_up(u, 1, 64);
  int carry = (lane == 0) ? BIGV : cf + 8 * (lane - 1);
  int f[8];
#pragma unroll
  for (int k = 0; k < 8; ++k) f[k] = min(ls[k], carry + k + 1);
  // backward scan
  int bs[8];
  bs[7] = f[7];
#pragma unroll
  for (int k = 6; k >= 0; --k) bs[k] = min(f[k], bs[k + 1] + 1);
  int mm = bs[0] + 8 * lane;
#pragma unroll
  for (int o = 1; o < 64; o <<= 1) {
    int t = __shfl_down(mm, o, 64);
    if (lane + o < 64) mm = min(mm, t);
  }
  int mb = __shfl_down(mm, 1, 64);
  int carryb = (lane == 63) ? BIGV : mb - 8 * lane;
  unsigned int lo = 0, hi = 0;
#pragma unroll
  for (int k = 0; k < 8; ++k) {
    int v = min(bs[k], carryb - k);
    if (k < 4) lo |= (unsigned int)v << (k * 8);
    else       hi |= (unsigned int)v << ((k - 4) * 8);
  }
  *(uint2*)(g_inter + ((size_t)(n * CC + c) * HH + h) * WW + lane * 8) =
      make_uint2(lo, hi);
}

// H-axis DT via chunked scan-then-propagate: thread owns a 64-row chunk of
// one column in registers; cross-chunk carries exchanged through LDS.
// Fused with the sparse border accumulation. Nothing written back.
__global__ __launch_bounds__(512) void k_coldt(const float* __restrict__ slices) {
  int plane = blockIdx.x >> 3;          // 152 planes
  int wt = blockIdx.x & 7;              // 8 w-tiles of 64
  int hc = threadIdx.x >> 6;            // 8 h-chunks of 64
  int wl = threadIdx.x & 63;
  int c = plane % CC;
  int n = plane / CC;
  int w = wt * 64 + wl;
  size_t pbase = (size_t)plane * HW;
  const unsigned char* colbase = g_inter + pbase + (size_t)(hc * 64) * WW + w;

  // load 64 chunk values (independent coalesced 64B wave-loads)
  int v[64];
#pragma unroll
  for (int k = 0; k < 64; ++k) v[k] = colbase[(size_t)k * WW];

  // local forward min-plus scan in place
#pragma unroll
  for (int k = 1; k < 64; ++k) v[k] = min(v[k], v[k - 1] + 1);

  __shared__ int s_car[8][64];
  s_car[hc][wl] = v[63];
  __syncthreads();
  // forward cross-chunk carry: F_in(i+1) = min(f63(i)+1, F_in(i)+64)
  int F = BIGV;
#pragma unroll
  for (int i = 0; i < 7; ++i)
    if (i < hc) F = min(s_car[i][wl] + 1, F + 64);
#pragma unroll
  for (int k = 0; k < 64; ++k) v[k] = min(v[k], F + k);

  // local backward scan in place
#pragma unroll
  for (int k = 62; k >= 0; --k) v[k] = min(v[k], v[k + 1] + 1);

  __syncthreads();
  s_car[hc][wl] = v[0];
  __syncthreads();
  // backward cross-chunk carry: B_in(i) = min(g0(i+1)+1, B_in(i+1)+64)
  int B = BIGV;
#pragma unroll
  for (int j = 7; j >= 1; --j)
    if (j > hc) B = min(s_car[j][wl] + 1, B + 64);

  // fused sparse accumulation
  float acc = 0.f;
#pragma unroll
  for (int k = 0; k < 64; ++k) {
    int out = min(v[k], B + (63 - k));
    int d = out - 5;                    // BORDER_DILATE
    if (d > 0) {
      int h = hc * 64 + k;
      int pix = (n * HH + h) * WW + w;
      int pcv = g_pred[pix];
      int pnv = (h + 1 < HH) ? g_pred[pix + WW] : pcv;
      int plv = (w > 0) ? g_pred[pix - 1] : pcv;
      bool ec = (pcv == c);
      if ((ec != (pnv == c)) || (ec != (plv == c))) {
        float x = slices[pbase + (size_t)h * WW + w];
        float smv = __expf(x - g_lse[pix]);
        acc += smv * (float)d;
      }
    }
  }

  __shared__ float sred[512];
  sred[threadIdx.x] = acc;
  __syncthreads();
  for (int s = 256; s > 0; s >>= 1) {
    if (threadIdx.x < s) sred[threadIdx.x] += sred[threadIdx.x + s];
    __syncthreads();
  }
  if (threadIdx.x == 0) atomicAdd(&g_acc[1], sred[0] * g_present[c]);
}

__global__ void k_final(float* __restrict__ out) {
  out[0] = g_acc[0] + sqrtf(g_acc[1]);   // BORDER_WEIGHT=1, power=0.5
}

extern "C" void kernel_launch(void* const* d_in, const int* in_sizes, int n_in,
                              void* d_out, int out_size, void* d_ws, size_t ws_size,
                              hipStream_t stream) {
  const float* slices = (const float*)d_in[0];
  const int* targets = (const int*)d_in[1];
  float* out = (float*)d_out;
  (void)d_ws; (void)ws_size; (void)in_sizes; (void)n_in; (void)out_size;

  hipLaunchKernelGGL(k_init, dim3(1), dim3(32), 0, stream);
  hipLaunchKernelGGL(k_pixel, dim3(2048), dim3(256), 0, stream, slices, targets);
  hipLaunchKernelGGL(k_rowdt, dim3((NN * CC * HH) / 4), dim3(256), 0, stream);
  hipLaunchKernelGGL(k_coldt, dim3(NPLANE * 8), dim3(512), 0, stream, slices);
  hipLaunchKernelGGL(k_final, dim3(1), dim3(1), 0, stream, out);
}